// Round 1
// baseline (231.937 us; speedup 1.0000x reference)
//
#include <hip/hip_runtime.h>
#include <math.h>

#define Bb 64
#define Nn 512
#define Dd 300

typedef __attribute__((ext_vector_type(8))) short bfrag;   // 8 bf16 = 4 VGPRs
typedef __attribute__((ext_vector_type(4))) float f4;      // MFMA accumulator
typedef __attribute__((ext_vector_type(4))) unsigned u4;
typedef __attribute__((ext_vector_type(2))) unsigned u2;

union BF { unsigned u[4]; bfrag v; u4 q; };

__device__ inline unsigned bfr(float x){            // f32 -> bf16 bits, RNE
    union{float f;unsigned u;}v; v.f=x;
    return (v.u + 0x7FFFu + ((v.u>>16)&1u))>>16;
}
__device__ inline unsigned pk_rne(float a, float b){ return bfr(a) | (bfr(b)<<16); }
__device__ inline unsigned pk_tr(float a, float b){  // truncation pack (cheap)
    union{float f;unsigned u;} ua, ub; ua.f=a; ub.f=b;
    return (ua.u>>16) | (ub.u & 0xFFFF0000u);
}
// W-frag bytes live in d_out slot bytes [608, 608+512) of slots f>>9
__device__ inline char* wadr(char* dout, unsigned f){
    return dout + (size_t)(f>>9)*1200u + 608u + (f&511u);
}
__device__ inline void async16(const char* g, char* l){
    __builtin_amdgcn_global_load_lds(
        (const __attribute__((address_space(1))) void*)g,
        (__attribute__((address_space(3))) void*)l, 16, 0, 0);
}

// Merged (b,mt) tile: 38400 B = [K zone 19200 | V zone 19200]
//  K: kc9 sub-tile [0,768): m*24 + (e-288)*2
//     kc<9:  768 + kc*2048 + ((e>>3)&3)*512 + m*16 + (e&7)*2
//  V: d<288:  19200 + (d>>4)*1024 + (m>>3)*256 + (d&15)*16 + (m&7)*2
//     d>=288: 19200 + 18432 + (m>>3)*192 + (d-288)*16 + (m&7)*2
#define TSZ 38400
#define VOFF 19200
#define ZSZ 19200

// ---------- Kernel A: concepts -> V zones  +  W -> bf16 frag-tiles ---------
// (former cast_cT grid (16,64)=1024 blocks) + (former wprep 40 blocks) merged
__global__ __launch_bounds__(256)
void prep(const float* __restrict__ concepts, char* __restrict__ tiles,
          const float* __restrict__ wq, const float* __restrict__ wk,
          char* __restrict__ dout)
{
    const int bx = blockIdx.x;
    const int t  = threadIdx.x;
    if (bx < 1024) {
        const int mt = bx & 15, b = bx >> 4;
        char* vz = tiles + ((size_t)(b*16 + mt))*TSZ + VOFF;
        for (int task = t; task < 300; task += 256) {
            int m8 = task / 75, d4 = task - m8*75;     // m8:0..3, d4:0..74
            const float* src = concepts + ((size_t)(b*Nn + mt*32 + m8*8))*Dd + d4*4;
            float4 r[8];
            #pragma unroll
            for (int i = 0; i < 8; ++i) r[i] = *(const float4*)(src + (size_t)i*Dd);
            #pragma unroll
            for (int dd = 0; dd < 4; ++dd) {
                int d = d4*4 + dd;
                float x[8];
                #pragma unroll
                for (int i = 0; i < 8; ++i)
                    x[i] = (dd==0) ? r[i].x : (dd==1) ? r[i].y : (dd==2) ? r[i].z : r[i].w;
                u4 q; q.x = pk_rne(x[0],x[1]); q.y = pk_rne(x[2],x[3]);
                      q.z = pk_rne(x[4],x[5]); q.w = pk_rne(x[6],x[7]);
                char* dst = (d < 288)
                    ? vz + (d>>4)*1024 + m8*256 + (d&15)*16
                    : vz + 18432 + m8*192 + (d-288)*16;
                *(u4*)dst = q;
            }
        }
    } else {
        // W prep: f = sel*194560 + kc*19456 + g*4864 + n*16 (+ (k&7)*2 inside)
        const int wid = bx - 1024;                 // 0..39
        const int xx = wid % 20, yy = wid / 20;
        const int sel = xx / 10, kc = xx % 10;
        const float* W = sel ? wk : wq;
        const int n = yy*152 + t;
        if (t < 152 && n < 304) {
            unsigned uu[16];
            #pragma unroll
            for (int j = 0; j < 16; ++j) uu[j] = 0;
            if (n < Dd) {
                const float* wr = W + (size_t)n*Dd + kc*32;
                int nv4 = (kc < 9) ? 8 : 3;        // kc=9: k 288..299 only
                #pragma unroll
                for (int i = 0; i < 8; ++i) {
                    if (i < nv4) {
                        float4 v = *(const float4*)(wr + i*4);
                        uu[2*i  ] = pk_rne(v.x, v.y);
                        uu[2*i+1] = pk_rne(v.z, v.w);
                    }
                }
            }
            unsigned fb = (unsigned)(sel*194560 + kc*19456 + n*16);
            #pragma unroll
            for (int g = 0; g < 4; ++g) {
                u4 q; q.x = uu[4*g+0]; q.y = uu[4*g+1]; q.z = uu[4*g+2]; q.w = uu[4*g+3];
                *(u4*)wadr(dout, fb + g*4864) = q;
            }
        }
    }
}

// ---------- Kernel C: projection GEMM, W staged via LDS dbuf ---------------
// Q is pre-scaled by 1/sqrt(300) here so attention needs no scale.
__global__ __launch_bounds__(256)
void proj4(const float* __restrict__ concepts, const float* __restrict__ ocr,
           const float* __restrict__ bq, const float* __restrict__ bk,
           char* __restrict__ dout, char* __restrict__ tiles)
{
    __shared__ char Wl[2][19456];
    const int t = threadIdx.x;
    const int w = t >> 6, lane = t & 63, ln = lane & 15, quad = lane >> 4;
    const int sel = blockIdx.y;
    const float* X    = sel ? ocr : concepts;
    const float* bias = sel ? bk  : bq;
    const int r0w = blockIdx.x*64 + w*16;
    const float* xr = X + (size_t)(r0w + ln)*Dd;

    const unsigned selbase = (unsigned)sel*194560u;
    #define STAGE_W(buf, kc) \
        for (int c = w; c < 19; c += 4) \
            async16((const char*)wadr(dout, selbase + (unsigned)(kc)*19456u + c*1024u + lane*16u), \
                    &Wl[buf][c*1024 + lane*16]);

    f4 acc[19];
    #pragma unroll
    for (int i = 0; i < 19; ++i) acc[i] = (f4){0.f,0.f,0.f,0.f};

    STAGE_W(0, 0);
    __syncthreads();

    for (int kc = 0; kc < 10; ++kc) {
        const int cur = kc & 1;
        if (kc < 9) { STAGE_W(1 - cur, kc + 1); }
        BF a;
        if (kc < 9) {
            float4 v0 = *(const float4*)(xr + kc*32 + quad*8);
            float4 v1 = *(const float4*)(xr + kc*32 + quad*8 + 4);
            a.u[0]=pk_tr(v0.x,v0.y); a.u[1]=pk_tr(v0.z,v0.w);
            a.u[2]=pk_tr(v1.x,v1.y); a.u[3]=pk_tr(v1.z,v1.w);
        } else {
            a.u[0]=0; a.u[1]=0; a.u[2]=0; a.u[3]=0;
            if (quad == 0) {
                float4 v0 = *(const float4*)(xr + 288);
                float4 v1 = *(const float4*)(xr + 292);
                a.u[0]=pk_tr(v0.x,v0.y); a.u[1]=pk_tr(v0.z,v0.w);
                a.u[2]=pk_tr(v1.x,v1.y); a.u[3]=pk_tr(v1.z,v1.w);
            } else if (quad == 1) {
                float4 v0 = *(const float4*)(xr + 296);
                a.u[0]=pk_tr(v0.x,v0.y); a.u[1]=pk_tr(v0.z,v0.w);
            }
        }
        #pragma unroll
        for (int nt = 0; nt < 19; ++nt) {
            BF bfv; bfv.q = *(const u4*)&Wl[cur][quad*4864 + nt*256 + ln*16];
            acc[nt] = __builtin_amdgcn_mfma_f32_16x16x32_bf16(a.v, bfv.v, acc[nt], 0,0,0);
        }
        __syncthreads();
    }

    const float QSCALE = 0.057735026918962584f;   // 1/sqrt(300)
    #pragma unroll
    for (int nt = 0; nt < 19; ++nt) {
        int e = nt*16 + ln;
        if (sel == 0) {
            #pragma unroll
            for (int reg = 0; reg < 4; ++reg) {
                int r = r0w + quad*4 + reg;
                short val = (e < Dd) ? (short)bfr((acc[nt][reg] + bias[e])*QSCALE) : (short)0;
                *(short*)(dout + (size_t)r*1200 + e*2) = val;   // e 300..303 zeroed
            }
        } else if (e < Dd) {
            float bv = bias[e];
            #pragma unroll
            for (int reg = 0; reg < 4; ++reg) {
                int r = r0w + quad*4 + reg;
                int b = r >> 9, m = r & 511, mt = m >> 5, ml = m & 31;
                char* tile = tiles + ((size_t)(b*16 + mt))*TSZ;
                short val = (short)bfr(acc[nt][reg] + bv);
                if (e < 288)
                    *(short*)(tile + 768 + (e>>5)*2048 + ((e>>3)&3)*512 + ml*16 + (e&7)*2) = val;
                else
                    *(short*)(tile + ml*24 + (e-288)*2) = val;
            }
        }
    }
}

// ---------- Kernel D: MFMA flash attention, ping-pong staged LDS -----------
// Scores = (Q*scale)@K^T ~ N(0,1): unnormalized softmax is f32-safe.
// 2-phase pipeline (T3 minimum recipe): every __syncthreads drains only
// loads issued one compute-phase earlier -> staging latency hidden.
//  LDS: K double-buffer (2 x 19200) + V single buffer (19200) = 57.6 KB,
//  still 2 blocks/CU (160K/57.6K) like before, but no dead-wait drains.
__global__ __launch_bounds__(256)
void attn6(char* __restrict__ dout, const char* __restrict__ tiles,
           const float* __restrict__ ocr, const int* __restrict__ mask,
           const float* __restrict__ lnw, const float* __restrict__ lnb)
{
    __shared__ __align__(16) char Kb0[ZSZ];
    __shared__ __align__(16) char Kb1[ZSZ];
    __shared__ __align__(16) char Vb[ZSZ];
    const int t = threadIdx.x;
    const int w = t >> 6, lane = t & 63, ln = lane & 15, quad = lane >> 4;
    const int b = blockIdx.x, n0 = blockIdx.y*64;  // same-b blocks share L2 set
    const int nlane = n0 + w*16 + ln;

    // Q B-frags from d_out low bytes (prescaled by 1/sqrt(300))
    const char* qb = dout + (size_t)(b*Nn + nlane)*1200;
    bfrag qf[10];
    #pragma unroll
    for (int kc = 0; kc < 9; ++kc)
        qf[kc] = *(const bfrag*)(qb + kc*64 + quad*16);
    {
        BF z; z.u[0]=z.u[1]=z.u[2]=z.u[3]=0;
        if (quad < 2) z.q = *(const u4*)(qb + 576 + quad*16);
        qf[9] = z.v;
    }

    f4 oacc[19];
    #pragma unroll
    for (int i = 0; i < 19; ++i) oacc[i] = (f4){0.f,0.f,0.f,0.f};
    float lrun = 0.f;
    const char* tb = tiles + (size_t)b*16*TSZ;

    // stage one 19200-B zone: 18 full 1KB chunks + 768-B tail (48 lanes)
#define STAGE_ZONE(SRC, DST) do { \
        const char* s_ = (SRC); char* d_ = (DST); \
        for (int c = w; c < 19; c += 4) \
            if (c < 18 || lane < 48) \
                async16(s_ + c*1024 + lane*16, d_ + c*1024 + lane*16); \
    } while (0)

    STAGE_ZONE(tb, Kb0);                 // K zone of tile 0
    __syncthreads();

    auto step = [&](int mt, const char* Kz, char* Kw) {
        // issue V(mt) stage; hidden under QK^T + softmax below
        STAGE_ZONE(tb + (size_t)mt*TSZ + VOFF, Vb);

        // S^T: A = K rows (m), B = Q  ->  C: row=m=quad*4+reg, col=n=ln
        f4 slo = (f4){0.f,0.f,0.f,0.f}, shi = (f4){0.f,0.f,0.f,0.f};
        __builtin_amdgcn_s_setprio(1);
        #pragma unroll
        for (int kc = 0; kc < 9; ++kc) {
            bfrag alo = *(const bfrag*)(Kz + 768 + kc*2048 + quad*512 + ln*16);
            bfrag ahi = *(const bfrag*)(Kz + 768 + kc*2048 + quad*512 + 256 + ln*16);
            slo = __builtin_amdgcn_mfma_f32_16x16x32_bf16(alo, qf[kc], slo, 0,0,0);
            shi = __builtin_amdgcn_mfma_f32_16x16x32_bf16(ahi, qf[kc], shi, 0,0,0);
        }
        {   // kc = 9 from 24B-row sub-tile (k>=300 garbage killed by Q zeros)
            BF alo, ahi;
            alo.u[0]=alo.u[1]=alo.u[2]=alo.u[3]=0;
            ahi.u[0]=ahi.u[1]=ahi.u[2]=ahi.u[3]=0;
            if (quad < 2) {
                u2 x0 = *(const u2*)(Kz + ln*24 + quad*16);
                u2 x1 = *(const u2*)(Kz + ln*24 + quad*16 + 8);
                alo.u[0]=x0.x; alo.u[1]=x0.y; alo.u[2]=x1.x; alo.u[3]=x1.y;
                u2 y0 = *(const u2*)(Kz + (16+ln)*24 + quad*16);
                u2 y1 = *(const u2*)(Kz + (16+ln)*24 + quad*16 + 8);
                ahi.u[0]=y0.x; ahi.u[1]=y0.y; ahi.u[2]=y1.x; ahi.u[3]=y1.y;
            }
            slo = __builtin_amdgcn_mfma_f32_16x16x32_bf16(alo.v, qf[9], slo, 0,0,0);
            shi = __builtin_amdgcn_mfma_f32_16x16x32_bf16(ahi.v, qf[9], shi, 0,0,0);
        }
        __builtin_amdgcn_s_setprio(0);

        // unnormalized softmax: p = exp(s), l += sum(p)  (register-only)
        float elo[4], ehi[4], ls = 0.f;
        #pragma unroll
        for (int reg = 0; reg < 4; ++reg) {
            elo[reg] = __expf(slo[reg]);
            ehi[reg] = __expf(shi[reg]);
            ls += elo[reg] + ehi[reg];
        }
        ls += __shfl_xor(ls, 16);
        ls += __shfl_xor(ls, 32);
        lrun += ls;

        // P: C-layout -> A-layout in-register (8 shfl + select)
        unsigned lo01 = pk_rne(elo[0], elo[1]), lo23 = pk_rne(elo[2], elo[3]);
        unsigned hi01 = pk_rne(ehi[0], ehi[1]), hi23 = pk_rne(ehi[2], ehi[3]);
        int sA = 2*(quad & 1)*16 + ln, sB = sA + 16;
        unsigned l0 = (unsigned)__shfl((int)lo01, sA);
        unsigned l1 = (unsigned)__shfl((int)lo23, sA);
        unsigned l2 = (unsigned)__shfl((int)lo01, sB);
        unsigned l3 = (unsigned)__shfl((int)lo23, sB);
        unsigned h0 = (unsigned)__shfl((int)hi01, sA);
        unsigned h1 = (unsigned)__shfl((int)hi23, sA);
        unsigned h2 = (unsigned)__shfl((int)hi01, sB);
        unsigned h3 = (unsigned)__shfl((int)hi23, sB);
        BF p;
        bool useHi = quad >= 2;
        p.u[0] = useHi ? h0 : l0; p.u[1] = useHi ? h1 : l1;
        p.u[2] = useHi ? h2 : l2; p.u[3] = useHi ? h3 : l3;

        __syncthreads();   // drains V(mt) loads (issued one phase ago);
                           // also: all warps done reading Kz

        // issue K(mt+1) stage; hidden under PV below, drained at tail barrier
        if (mt < 15) STAGE_ZONE(tb + (size_t)(mt+1)*TSZ, Kw);

        // O += P V : B-frags from V zone (lane-linear layout)
        __builtin_amdgcn_s_setprio(1);
        #pragma unroll
        for (int nt = 0; nt < 18; ++nt) {
            bfrag vf = *(const bfrag*)(Vb + nt*1024 + lane*16);
            oacc[nt] = __builtin_amdgcn_mfma_f32_16x16x32_bf16(p.v, vf, oacc[nt], 0,0,0);
        }
        {   // nt = 18: d 288..303, ln >= 12 has no storage -> zero frag
            BF vf; vf.u[0]=vf.u[1]=vf.u[2]=vf.u[3]=0;
            if (ln < 12) vf.q = *(const u4*)(Vb + 18432 + quad*192 + ln*16);
            oacc[18] = __builtin_amdgcn_mfma_f32_16x16x32_bf16(p.v, vf.v, oacc[18], 0,0,0);
        }
        __builtin_amdgcn_s_setprio(0);

        __syncthreads();   // drains K(mt+1) loads; Vb free for next stage
    };

    for (int mt2 = 0; mt2 < 16; mt2 += 2) {
        step(mt2,     Kb0, Kb1);
        step(mt2 + 1, Kb1, Kb0);
    }

    // epilogue: rows n = quad*4+reg; cols d = nt*16+ln
    float invl[4];
    #pragma unroll
    for (int reg = 0; reg < 4; ++reg) invl[reg] = 1.0f / __shfl(lrun, quad*4 + reg);
    #pragma unroll
    for (int reg = 0; reg < 4; ++reg) {
        int r = b*Nn + n0 + w*16 + quad*4 + reg;
        int mr = mask[r];
        float xs[19], s = 0.f, ss = 0.f;
        #pragma unroll
        for (int nt = 0; nt < 19; ++nt) {
            int d = nt*16 + ln;
            float x = 0.f;
            if (d < Dd) x = oacc[nt][reg]*invl[reg] + ocr[(size_t)r*Dd + d];
            xs[nt] = x; s += x; ss += x*x;
        }
        #pragma unroll
        for (int off = 1; off < 16; off <<= 1) {
            s += __shfl_xor(s, off); ss += __shfl_xor(ss, off);
        }
        float mu   = s * (1.0f/Dd);
        float var  = ss * (1.0f/Dd) - mu*mu;
        float rstd = rsqrtf(var + 1e-5f);
        #pragma unroll
        for (int nt = 0; nt < 19; ++nt) {
            int d = nt*16 + ln;
            if (d < Dd) {
                // masked rows: +lnw+lnb (verified rounds 1-3)
                float y = mr ? (xs[nt]-mu)*rstd*lnw[d] + lnb[d] : lnw[d] + lnb[d];
                *(float*)(dout + (size_t)r*1200 + d*4) = y;
            }
        }
    }
}

extern "C" void kernel_launch(void* const* d_in, const int* in_sizes, int n_in,
                              void* d_out, int out_size, void* d_ws, size_t ws_size,
                              hipStream_t stream)
{
    const float* concepts = (const float*)d_in[0];
    const float* ocr      = (const float*)d_in[1];
    const int*   mask     = (const int*)d_in[2];
    const float* wq  = (const float*)d_in[3];
    const float* bq  = (const float*)d_in[4];
    const float* wk  = (const float*)d_in[5];
    const float* bk  = (const float*)d_in[6];
    const float* lnw = (const float*)d_in[7];
    const float* lnb = (const float*)d_in[8];

    char* dout  = (char*)d_out;
    char* tiles = (char*)d_ws;   // 1024 merged tiles x 38400 B = 39,321,600 B

    prep <<<dim3(1064),    256, 0, stream>>>(concepts, tiles, wq, wk, dout);
    proj4<<<dim3(512, 2),  256, 0, stream>>>(concepts, ocr, bq, bk, dout, tiles);
    attn6<<<dim3(64, 8),   256, 0, stream>>>(dout, tiles, ocr, mask, lnw, lnb);
}

// Round 2
// 228.155 us; speedup vs baseline: 1.0166x; 1.0166x over previous
//
#include <hip/hip_runtime.h>
#include <math.h>

#define Bb 64
#define Nn 512
#define Dd 300

typedef __attribute__((ext_vector_type(8))) short bfrag;   // 8 bf16 = 4 VGPRs
typedef __attribute__((ext_vector_type(4))) float f4;      // MFMA accumulator
typedef __attribute__((ext_vector_type(4))) unsigned u4;
typedef __attribute__((ext_vector_type(2))) unsigned u2;

union BF { unsigned u[4]; bfrag v; u4 q; };

__device__ inline unsigned bfr(float x){            // f32 -> bf16 bits, RNE
    union{float f;unsigned u;}v; v.f=x;
    return (v.u + 0x7FFFu + ((v.u>>16)&1u))>>16;
}
__device__ inline unsigned pk_rne(float a, float b){ return bfr(a) | (bfr(b)<<16); }
__device__ inline unsigned pk_tr(float a, float b){  // truncation pack (cheap)
    union{float f;unsigned u;} ua, ub; ua.f=a; ub.f=b;
    return (ua.u>>16) | (ub.u & 0xFFFF0000u);
}
// W-frag bytes live in d_out slot bytes [608, 608+512) of slots f>>9
__device__ inline char* wadr(char* dout, unsigned f){
    return dout + (size_t)(f>>9)*1200u + 608u + (f&511u);
}
__device__ inline void async16(const char* g, char* l){
    __builtin_amdgcn_global_load_lds(
        (const __attribute__((address_space(1))) void*)g,
        (__attribute__((address_space(3))) void*)l, 16, 0, 0);
}

// Merged (b,mt) tile: 38400 B = [K zone 19200 | V zone 19200]
//  K: kc9 sub-tile [0,768): m*24 + (e-288)*2
//     kc<9:  768 + kc*2048 + ((e>>3)&3)*512 + m*16 + (e&7)*2
//  V: d<288:  19200 + (d>>4)*1024 + (m>>3)*256 + (d&15)*16 + (m&7)*2
//     d>=288: 19200 + 18432 + (m>>3)*192 + (d-288)*16 + (m&7)*2
#define TSZ 38400
#define VOFF 19200
#define ZSZ 19200

// ---------- Kernel A: concepts -> V zones  +  W -> bf16 frag-tiles ---------
__global__ __launch_bounds__(256)
void prep(const float* __restrict__ concepts, char* __restrict__ tiles,
          const float* __restrict__ wq, const float* __restrict__ wk,
          char* __restrict__ dout)
{
    const int bx = blockIdx.x;
    const int t  = threadIdx.x;
    if (bx < 1024) {
        const int mt = bx & 15, b = bx >> 4;
        char* vz = tiles + ((size_t)(b*16 + mt))*TSZ + VOFF;
        for (int task = t; task < 300; task += 256) {
            int m8 = task / 75, d4 = task - m8*75;     // m8:0..3, d4:0..74
            const float* src = concepts + ((size_t)(b*Nn + mt*32 + m8*8))*Dd + d4*4;
            float4 r[8];
            #pragma unroll
            for (int i = 0; i < 8; ++i) r[i] = *(const float4*)(src + (size_t)i*Dd);
            #pragma unroll
            for (int dd = 0; dd < 4; ++dd) {
                int d = d4*4 + dd;
                float x[8];
                #pragma unroll
                for (int i = 0; i < 8; ++i)
                    x[i] = (dd==0) ? r[i].x : (dd==1) ? r[i].y : (dd==2) ? r[i].z : r[i].w;
                u4 q; q.x = pk_rne(x[0],x[1]); q.y = pk_rne(x[2],x[3]);
                      q.z = pk_rne(x[4],x[5]); q.w = pk_rne(x[6],x[7]);
                char* dst = (d < 288)
                    ? vz + (d>>4)*1024 + m8*256 + (d&15)*16
                    : vz + 18432 + m8*192 + (d-288)*16;
                *(u4*)dst = q;
            }
        }
    } else {
        // W prep: f = sel*194560 + kc*19456 + g*4864 + n*16 (+ (k&7)*2 inside)
        const int wid = bx - 1024;                 // 0..39
        const int xx = wid % 20, yy = wid / 20;
        const int sel = xx / 10, kc = xx % 10;
        const float* W = sel ? wk : wq;
        const int n = yy*152 + t;
        if (t < 152 && n < 304) {
            unsigned uu[16];
            #pragma unroll
            for (int j = 0; j < 16; ++j) uu[j] = 0;
            if (n < Dd) {
                const float* wr = W + (size_t)n*Dd + kc*32;
                int nv4 = (kc < 9) ? 8 : 3;        // kc=9: k 288..299 only
                #pragma unroll
                for (int i = 0; i < 8; ++i) {
                    if (i < nv4) {
                        float4 v = *(const float4*)(wr + i*4);
                        uu[2*i  ] = pk_rne(v.x, v.y);
                        uu[2*i+1] = pk_rne(v.z, v.w);
                    }
                }
            }
            unsigned fb = (unsigned)(sel*194560 + kc*19456 + n*16);
            #pragma unroll
            for (int g = 0; g < 4; ++g) {
                u4 q; q.x = uu[4*g+0]; q.y = uu[4*g+1]; q.z = uu[4*g+2]; q.w = uu[4*g+3];
                *(u4*)wadr(dout, fb + g*4864) = q;
            }
        }
    }
}

// ---------- Kernel C: projection GEMM, W staged via LDS dbuf ---------------
// Q is pre-scaled by 1/sqrt(300) here so attention needs no scale.
__global__ __launch_bounds__(256)
void proj4(const float* __restrict__ concepts, const float* __restrict__ ocr,
           const float* __restrict__ bq, const float* __restrict__ bk,
           char* __restrict__ dout, char* __restrict__ tiles)
{
    __shared__ char Wl[2][19456];
    const int t = threadIdx.x;
    const int w = t >> 6, lane = t & 63, ln = lane & 15, quad = lane >> 4;
    const int sel = blockIdx.y;
    const float* X    = sel ? ocr : concepts;
    const float* bias = sel ? bk  : bq;
    const int r0w = blockIdx.x*64 + w*16;
    const float* xr = X + (size_t)(r0w + ln)*Dd;

    const unsigned selbase = (unsigned)sel*194560u;
    #define STAGE_W(buf, kc) \
        for (int c = w; c < 19; c += 4) \
            async16((const char*)wadr(dout, selbase + (unsigned)(kc)*19456u + c*1024u + lane*16u), \
                    &Wl[buf][c*1024 + lane*16]);

    f4 acc[19];
    #pragma unroll
    for (int i = 0; i < 19; ++i) acc[i] = (f4){0.f,0.f,0.f,0.f};

    STAGE_W(0, 0);
    __syncthreads();

    for (int kc = 0; kc < 10; ++kc) {
        const int cur = kc & 1;
        if (kc < 9) { STAGE_W(1 - cur, kc + 1); }
        BF a;
        if (kc < 9) {
            float4 v0 = *(const float4*)(xr + kc*32 + quad*8);
            float4 v1 = *(const float4*)(xr + kc*32 + quad*8 + 4);
            a.u[0]=pk_tr(v0.x,v0.y); a.u[1]=pk_tr(v0.z,v0.w);
            a.u[2]=pk_tr(v1.x,v1.y); a.u[3]=pk_tr(v1.z,v1.w);
        } else {
            a.u[0]=0; a.u[1]=0; a.u[2]=0; a.u[3]=0;
            if (quad == 0) {
                float4 v0 = *(const float4*)(xr + 288);
                float4 v1 = *(const float4*)(xr + 292);
                a.u[0]=pk_tr(v0.x,v0.y); a.u[1]=pk_tr(v0.z,v0.w);
                a.u[2]=pk_tr(v1.x,v1.y); a.u[3]=pk_tr(v1.z,v1.w);
            } else if (quad == 1) {
                float4 v0 = *(const float4*)(xr + 296);
                a.u[0]=pk_tr(v0.x,v0.y); a.u[1]=pk_tr(v0.z,v0.w);
            }
        }
        #pragma unroll
        for (int nt = 0; nt < 19; ++nt) {
            BF bfv; bfv.q = *(const u4*)&Wl[cur][quad*4864 + nt*256 + ln*16];
            acc[nt] = __builtin_amdgcn_mfma_f32_16x16x32_bf16(a.v, bfv.v, acc[nt], 0,0,0);
        }
        __syncthreads();
    }

    const float QSCALE = 0.057735026918962584f;   // 1/sqrt(300)
    #pragma unroll
    for (int nt = 0; nt < 19; ++nt) {
        int e = nt*16 + ln;
        if (sel == 0) {
            #pragma unroll
            for (int reg = 0; reg < 4; ++reg) {
                int r = r0w + quad*4 + reg;
                short val = (e < Dd) ? (short)bfr((acc[nt][reg] + bias[e])*QSCALE) : (short)0;
                *(short*)(dout + (size_t)r*1200 + e*2) = val;   // e 300..303 zeroed
            }
        } else if (e < Dd) {
            float bv = bias[e];
            #pragma unroll
            for (int reg = 0; reg < 4; ++reg) {
                int r = r0w + quad*4 + reg;
                int b = r >> 9, m = r & 511, mt = m >> 5, ml = m & 31;
                char* tile = tiles + ((size_t)(b*16 + mt))*TSZ;
                short val = (short)bfr(acc[nt][reg] + bv);
                if (e < 288)
                    *(short*)(tile + 768 + (e>>5)*2048 + ((e>>3)&3)*512 + ml*16 + (e&7)*2) = val;
                else
                    *(short*)(tile + ml*24 + (e-288)*2) = val;
            }
        }
    }
}

// ---------- Kernel D: MFMA flash attention, V reg-prefetch, 1 barrier/mt ---
// K: LDS double-buffer (2 x 19200 = 38.4 KB). Stage K(mt+1) issued at phase
// top, drained by the single end-of-phase barrier a full QK^T+softmax+PV
// later -> L3 latency hidden. V: no LDS at all -- prefetched to 19 register
// frags at phase top (T14), coalesced 1KB global reads, consumed by PV after
// ~700 cyc of register-only work. Barriers per block: 33 -> 17.
__global__ __launch_bounds__(256, 2)
void attn7(char* __restrict__ dout, const char* __restrict__ tiles,
           const float* __restrict__ ocr, const int* __restrict__ mask,
           const float* __restrict__ lnw, const float* __restrict__ lnb)
{
    __shared__ __align__(16) char Kb[2][ZSZ];
    const int t = threadIdx.x;
    const int w = t >> 6, lane = t & 63, ln = lane & 15, quad = lane >> 4;
    const int b = blockIdx.x, n0 = blockIdx.y*64;  // all y-blocks of b share an XCD
    const int nlane = n0 + w*16 + ln;

    // Q B-frags from d_out low bytes (prescaled by 1/sqrt(300))
    const char* qb = dout + (size_t)(b*Nn + nlane)*1200;
    bfrag qf[10];
    #pragma unroll
    for (int kc = 0; kc < 9; ++kc)
        qf[kc] = *(const bfrag*)(qb + kc*64 + quad*16);
    {
        BF z; z.u[0]=z.u[1]=z.u[2]=z.u[3]=0;
        if (quad < 2) z.q = *(const u4*)(qb + 576 + quad*16);
        qf[9] = z.v;
    }

    f4 oacc[19];
    #pragma unroll
    for (int i = 0; i < 19; ++i) oacc[i] = (f4){0.f,0.f,0.f,0.f};
    float lrun = 0.f;
    const char* tb = tiles + (size_t)b*16*TSZ;

    // stage one 19200-B K zone: 18 full 1KB chunks + 768-B tail (48 lanes)
#define STAGE_ZONE(SRC, DST) do { \
        const char* s_ = (SRC); char* d_ = (DST); \
        for (int c = w; c < 19; c += 4) \
            if (c < 18 || lane < 48) \
                async16(s_ + c*1024 + lane*16, d_ + c*1024 + lane*16); \
    } while (0)

    STAGE_ZONE(tb, Kb[0]);               // K zone of tile 0
    __syncthreads();

    for (int mt = 0; mt < 16; ++mt) {
        const char* Kz = Kb[mt & 1];
        char*       Kw = Kb[1 - (mt & 1)];
        const char* Vg = tb + (size_t)mt*TSZ + VOFF;

        // V(mt) -> registers (coalesced 1KB loads); consumed after QK^T+softmax
        BF vf[19];
        #pragma unroll
        for (int nt = 0; nt < 18; ++nt)
            vf[nt].q = *(const u4*)(Vg + nt*1024 + lane*16);
        {   // nt = 18: d 288..303, ln >= 12 has no storage -> zero frag
            vf[18].u[0]=0; vf[18].u[1]=0; vf[18].u[2]=0; vf[18].u[3]=0;
            if (ln < 12) vf[18].q = *(const u4*)(Vg + 18432 + quad*192 + ln*16);
        }

        // issue K(mt+1) stage; drained at this phase's tail barrier
        if (mt < 15) STAGE_ZONE(tb + (size_t)(mt+1)*TSZ, Kw);

        // S^T: A = K rows (m), B = Q  ->  C: row=m=quad*4+reg, col=n=ln
        f4 slo = (f4){0.f,0.f,0.f,0.f}, shi = (f4){0.f,0.f,0.f,0.f};
        __builtin_amdgcn_s_setprio(1);
        #pragma unroll
        for (int kc = 0; kc < 9; ++kc) {
            bfrag alo = *(const bfrag*)(Kz + 768 + kc*2048 + quad*512 + ln*16);
            bfrag ahi = *(const bfrag*)(Kz + 768 + kc*2048 + quad*512 + 256 + ln*16);
            slo = __builtin_amdgcn_mfma_f32_16x16x32_bf16(alo, qf[kc], slo, 0,0,0);
            shi = __builtin_amdgcn_mfma_f32_16x16x32_bf16(ahi, qf[kc], shi, 0,0,0);
        }
        {   // kc = 9 from 24B-row sub-tile (k>=300 garbage killed by Q zeros)
            BF alo, ahi;
            alo.u[0]=alo.u[1]=alo.u[2]=alo.u[3]=0;
            ahi.u[0]=ahi.u[1]=ahi.u[2]=ahi.u[3]=0;
            if (quad < 2) {
                u2 x0 = *(const u2*)(Kz + ln*24 + quad*16);
                u2 x1 = *(const u2*)(Kz + ln*24 + quad*16 + 8);
                alo.u[0]=x0.x; alo.u[1]=x0.y; alo.u[2]=x1.x; alo.u[3]=x1.y;
                u2 y0 = *(const u2*)(Kz + (16+ln)*24 + quad*16);
                u2 y1 = *(const u2*)(Kz + (16+ln)*24 + quad*16 + 8);
                ahi.u[0]=y0.x; ahi.u[1]=y0.y; ahi.u[2]=y1.x; ahi.u[3]=y1.y;
            }
            slo = __builtin_amdgcn_mfma_f32_16x16x32_bf16(alo.v, qf[9], slo, 0,0,0);
            shi = __builtin_amdgcn_mfma_f32_16x16x32_bf16(ahi.v, qf[9], shi, 0,0,0);
        }
        __builtin_amdgcn_s_setprio(0);

        // unnormalized softmax: p = exp(s), l += sum(p)  (register-only)
        float elo[4], ehi[4], ls = 0.f;
        #pragma unroll
        for (int reg = 0; reg < 4; ++reg) {
            elo[reg] = __expf(slo[reg]);
            ehi[reg] = __expf(shi[reg]);
            ls += elo[reg] + ehi[reg];
        }
        ls += __shfl_xor(ls, 16);
        ls += __shfl_xor(ls, 32);
        lrun += ls;

        // P: C-layout -> A-layout in-register (8 shfl + select)
        unsigned lo01 = pk_rne(elo[0], elo[1]), lo23 = pk_rne(elo[2], elo[3]);
        unsigned hi01 = pk_rne(ehi[0], ehi[1]), hi23 = pk_rne(ehi[2], ehi[3]);
        int sA = 2*(quad & 1)*16 + ln, sB = sA + 16;
        unsigned l0 = (unsigned)__shfl((int)lo01, sA);
        unsigned l1 = (unsigned)__shfl((int)lo23, sA);
        unsigned l2 = (unsigned)__shfl((int)lo01, sB);
        unsigned l3 = (unsigned)__shfl((int)lo23, sB);
        unsigned h0 = (unsigned)__shfl((int)hi01, sA);
        unsigned h1 = (unsigned)__shfl((int)hi23, sA);
        unsigned h2 = (unsigned)__shfl((int)hi01, sB);
        unsigned h3 = (unsigned)__shfl((int)hi23, sB);
        BF p;
        bool useHi = quad >= 2;
        p.u[0] = useHi ? h0 : l0; p.u[1] = useHi ? h1 : l1;
        p.u[2] = useHi ? h2 : l2; p.u[3] = useHi ? h3 : l3;

        // O += P V : B-frags from V register prefetch (vmcnt waits here)
        __builtin_amdgcn_s_setprio(1);
        #pragma unroll
        for (int nt = 0; nt < 19; ++nt)
            oacc[nt] = __builtin_amdgcn_mfma_f32_16x16x32_bf16(p.v, vf[nt].v, oacc[nt], 0,0,0);
        __builtin_amdgcn_s_setprio(0);

        __syncthreads();   // drains K(mt+1) stage (issued a full phase ago);
                           // gates Kz overwrite at mt+1
    }

    // epilogue: rows n = quad*4+reg; cols d = nt*16+ln
    float invl[4];
    #pragma unroll
    for (int reg = 0; reg < 4; ++reg) invl[reg] = 1.0f / __shfl(lrun, quad*4 + reg);
    #pragma unroll
    for (int reg = 0; reg < 4; ++reg) {
        int r = b*Nn + n0 + w*16 + quad*4 + reg;
        int mr = mask[r];
        float xs[19], s = 0.f, ss = 0.f;
        #pragma unroll
        for (int nt = 0; nt < 19; ++nt) {
            int d = nt*16 + ln;
            float x = 0.f;
            if (d < Dd) x = oacc[nt][reg]*invl[reg] + ocr[(size_t)r*Dd + d];
            xs[nt] = x; s += x; ss += x*x;
        }
        #pragma unroll
        for (int off = 1; off < 16; off <<= 1) {
            s += __shfl_xor(s, off); ss += __shfl_xor(ss, off);
        }
        float mu   = s * (1.0f/Dd);
        float var  = ss * (1.0f/Dd) - mu*mu;
        float rstd = rsqrtf(var + 1e-5f);
        #pragma unroll
        for (int nt = 0; nt < 19; ++nt) {
            int d = nt*16 + ln;
            if (d < Dd) {
                // masked rows: +lnw+lnb (verified rounds 1-3)
                float y = mr ? (xs[nt]-mu)*rstd*lnw[d] + lnb[d] : lnw[d] + lnb[d];
                *(float*)(dout + (size_t)r*1200 + d*4) = y;
            }
        }
    }
}

extern "C" void kernel_launch(void* const* d_in, const int* in_sizes, int n_in,
                              void* d_out, int out_size, void* d_ws, size_t ws_size,
                              hipStream_t stream)
{
    const float* concepts = (const float*)d_in[0];
    const float* ocr      = (const float*)d_in[1];
    const int*   mask     = (const int*)d_in[2];
    const float* wq  = (const float*)d_in[3];
    const float* bq  = (const float*)d_in[4];
    const float* wk  = (const float*)d_in[5];
    const float* bk  = (const float*)d_in[6];
    const float* lnw = (const float*)d_in[7];
    const float* lnb = (const float*)d_in[8];

    char* dout  = (char*)d_out;
    char* tiles = (char*)d_ws;   // 1024 merged tiles x 38400 B = 39,321,600 B

    prep <<<dim3(1064),    256, 0, stream>>>(concepts, tiles, wq, wk, dout);
    proj4<<<dim3(512, 2),  256, 0, stream>>>(concepts, ocr, bq, bk, dout, tiles);
    attn7<<<dim3(64, 8),   256, 0, stream>>>(dout, tiles, ocr, mask, lnw, lnb);
}

// Round 4
// 226.904 us; speedup vs baseline: 1.0222x; 1.0055x over previous
//
#include <hip/hip_runtime.h>
#include <math.h>

#define Bb 64
#define Nn 512
#define Dd 300

typedef __attribute__((ext_vector_type(8))) short bfrag;   // 8 bf16 = 4 VGPRs
typedef __attribute__((ext_vector_type(4))) float f4;      // MFMA accumulator
typedef __attribute__((ext_vector_type(4))) unsigned u4;
typedef __attribute__((ext_vector_type(2))) unsigned u2;

union BF { unsigned u[4]; bfrag v; u4 q; };

__device__ inline unsigned bfr(float x){            // f32 -> bf16 bits, RNE
    union{float f;unsigned u;}v; v.f=x;
    return (v.u + 0x7FFFu + ((v.u>>16)&1u))>>16;
}
__device__ inline unsigned pk_rne(float a, float b){ return bfr(a) | (bfr(b)<<16); }
__device__ inline unsigned pk_tr(float a, float b){  // truncation pack (cheap)
    union{float f;unsigned u;} ua, ub; ua.f=a; ub.f=b;
    return (ua.u>>16) | (ub.u & 0xFFFF0000u);
}
// W-frag bytes live in d_out slot bytes [608, 608+512) of slots f>>9
__device__ inline char* wadr(char* dout, unsigned f){
    return dout + (size_t)(f>>9)*1200u + 608u + (f&511u);
}
__device__ inline void async16(const char* g, char* l){
    __builtin_amdgcn_global_load_lds(
        (const __attribute__((address_space(1))) void*)g,
        (__attribute__((address_space(3))) void*)l, 16, 0, 0);
}

// Merged (b,mt) tile: 38400 B = [K zone 19200 | V zone 19200]
//  K: kc9 sub-tile [0,768): m*24 + (e-288)*2
//     kc<9:  768 + kc*2048 + ((e>>3)&3)*512 + m*16 + (e&7)*2
//  V: d<288:  19200 + (d>>4)*1024 + (m>>3)*256 + (d&15)*16 + (m&7)*2
//     d>=288: 19200 + 18432 + (m>>3)*192 + (d-288)*16 + (m&7)*2
#define TSZ 38400
#define VOFF 19200

// ---------- Kernel A: concepts -> V zones  +  W -> bf16 frag-tiles ---------
__global__ __launch_bounds__(256)
void prep(const float* __restrict__ concepts, char* __restrict__ tiles,
          const float* __restrict__ wq, const float* __restrict__ wk,
          char* __restrict__ dout)
{
    const int bx = blockIdx.x;
    const int t  = threadIdx.x;
    if (bx < 1024) {
        const int mt = bx & 15, b = bx >> 4;
        char* vz = tiles + ((size_t)(b*16 + mt))*TSZ + VOFF;
        for (int task = t; task < 300; task += 256) {
            int m8 = task / 75, d4 = task - m8*75;     // m8:0..3, d4:0..74
            const float* src = concepts + ((size_t)(b*Nn + mt*32 + m8*8))*Dd + d4*4;
            float4 r[8];
            #pragma unroll
            for (int i = 0; i < 8; ++i) r[i] = *(const float4*)(src + (size_t)i*Dd);
            #pragma unroll
            for (int dd = 0; dd < 4; ++dd) {
                int d = d4*4 + dd;
                float x[8];
                #pragma unroll
                for (int i = 0; i < 8; ++i)
                    x[i] = (dd==0) ? r[i].x : (dd==1) ? r[i].y : (dd==2) ? r[i].z : r[i].w;
                u4 q; q.x = pk_rne(x[0],x[1]); q.y = pk_rne(x[2],x[3]);
                      q.z = pk_rne(x[4],x[5]); q.w = pk_rne(x[6],x[7]);
                char* dst = (d < 288)
                    ? vz + (d>>4)*1024 + m8*256 + (d&15)*16
                    : vz + 18432 + m8*192 + (d-288)*16;
                *(u4*)dst = q;
            }
        }
    } else {
        // W prep: f = sel*194560 + kc*19456 + g*4864 + n*16 (+ (k&7)*2 inside)
        const int wid = bx - 1024;                 // 0..39
        const int xx = wid % 20, yy = wid / 20;
        const int sel = xx / 10, kc = xx % 10;
        const float* W = sel ? wk : wq;
        const int n = yy*152 + t;
        if (t < 152 && n < 304) {
            unsigned uu[16];
            #pragma unroll
            for (int j = 0; j < 16; ++j) uu[j] = 0;
            if (n < Dd) {
                const float* wr = W + (size_t)n*Dd + kc*32;
                int nv4 = (kc < 9) ? 8 : 3;        // kc=9: k 288..299 only
                #pragma unroll
                for (int i = 0; i < 8; ++i) {
                    if (i < nv4) {
                        float4 v = *(const float4*)(wr + i*4);
                        uu[2*i  ] = pk_rne(v.x, v.y);
                        uu[2*i+1] = pk_rne(v.z, v.w);
                    }
                }
            }
            unsigned fb = (unsigned)(sel*194560 + kc*19456 + n*16);
            #pragma unroll
            for (int g = 0; g < 4; ++g) {
                u4 q; q.x = uu[4*g+0]; q.y = uu[4*g+1]; q.z = uu[4*g+2]; q.w = uu[4*g+3];
                *(u4*)wadr(dout, fb + g*4864) = q;
            }
        }
    }
}

// ---------- Kernel C: projection GEMM, W staged via LDS dbuf ---------------
// Q is pre-scaled by 1/sqrt(300) here so attention needs no scale.
__global__ __launch_bounds__(256)
void proj4(const float* __restrict__ concepts, const float* __restrict__ ocr,
           const float* __restrict__ bq, const float* __restrict__ bk,
           char* __restrict__ dout, char* __restrict__ tiles)
{
    __shared__ char Wl[2][19456];
    const int t = threadIdx.x;
    const int w = t >> 6, lane = t & 63, ln = lane & 15, quad = lane >> 4;
    const int sel = blockIdx.y;
    const float* X    = sel ? ocr : concepts;
    const float* bias = sel ? bk  : bq;
    const int r0w = blockIdx.x*64 + w*16;
    const float* xr = X + (size_t)(r0w + ln)*Dd;

    const unsigned selbase = (unsigned)sel*194560u;
    #define STAGE_W(buf, kc) \
        for (int c = w; c < 19; c += 4) \
            async16((const char*)wadr(dout, selbase + (unsigned)(kc)*19456u + c*1024u + lane*16u), \
                    &Wl[buf][c*1024 + lane*16]);

    f4 acc[19];
    #pragma unroll
    for (int i = 0; i < 19; ++i) acc[i] = (f4){0.f,0.f,0.f,0.f};

    STAGE_W(0, 0);
    __syncthreads();

    for (int kc = 0; kc < 10; ++kc) {
        const int cur = kc & 1;
        if (kc < 9) { STAGE_W(1 - cur, kc + 1); }
        BF a;
        if (kc < 9) {
            float4 v0 = *(const float4*)(xr + kc*32 + quad*8);
            float4 v1 = *(const float4*)(xr + kc*32 + quad*8 + 4);
            a.u[0]=pk_tr(v0.x,v0.y); a.u[1]=pk_tr(v0.z,v0.w);
            a.u[2]=pk_tr(v1.x,v1.y); a.u[3]=pk_tr(v1.z,v1.w);
        } else {
            a.u[0]=0; a.u[1]=0; a.u[2]=0; a.u[3]=0;
            if (quad == 0) {
                float4 v0 = *(const float4*)(xr + 288);
                float4 v1 = *(const float4*)(xr + 292);
                a.u[0]=pk_tr(v0.x,v0.y); a.u[1]=pk_tr(v0.z,v0.w);
                a.u[2]=pk_tr(v1.x,v1.y); a.u[3]=pk_tr(v1.z,v1.w);
            } else if (quad == 1) {
                float4 v0 = *(const float4*)(xr + 296);
                a.u[0]=pk_tr(v0.x,v0.y); a.u[1]=pk_tr(v0.z,v0.w);
            }
        }
        #pragma unroll
        for (int nt = 0; nt < 19; ++nt) {
            BF bfv; bfv.q = *(const u4*)&Wl[cur][quad*4864 + nt*256 + ln*16];
            acc[nt] = __builtin_amdgcn_mfma_f32_16x16x32_bf16(a.v, bfv.v, acc[nt], 0,0,0);
        }
        __syncthreads();
    }

    const float QSCALE = 0.057735026918962584f;   // 1/sqrt(300)
    #pragma unroll
    for (int nt = 0; nt < 19; ++nt) {
        int e = nt*16 + ln;
        if (sel == 0) {
            #pragma unroll
            for (int reg = 0; reg < 4; ++reg) {
                int r = r0w + quad*4 + reg;
                short val = (e < Dd) ? (short)bfr((acc[nt][reg] + bias[e])*QSCALE) : (short)0;
                *(short*)(dout + (size_t)r*1200 + e*2) = val;   // e 300..303 zeroed
            }
        } else if (e < Dd) {
            float bv = bias[e];
            #pragma unroll
            for (int reg = 0; reg < 4; ++reg) {
                int r = r0w + quad*4 + reg;
                int b = r >> 9, m = r & 511, mt = m >> 5, ml = m & 31;
                char* tile = tiles + ((size_t)(b*16 + mt))*TSZ;
                short val = (short)bfr(acc[nt][reg] + bv);
                if (e < 288)
                    *(short*)(tile + 768 + (e>>5)*2048 + ((e>>3)&3)*512 + ml*16 + (e&7)*2) = val;
                else
                    *(short*)(tile + ml*24 + (e-288)*2) = val;
            }
        }
    }
}

// ---------- Kernel D: 8-wave flash attention, tile staged once per block ---
// Rounds 0-2 showed attn is NOT barrier- or BW-bound: it is line-miss (MLP)
// bound -- per-CU phases x line-misses/phase is the cost. This version:
//  - 512-thread / 8-wave blocks, 128 Q rows each -> grid (64,4) = 1 block/CU
//  - full 38.4 KB merged tile staged ONCE per phase for all 8 waves
//    (per-CU line-misses: 48K -> 9.6K; per-CU phases: 32 -> 16)
//  - keeps attn7's single-barrier double-buffer schedule (LDS 76.8 KB)
// Round-3 bugfix: 38400 = 37*1024 + 512 -> tail chunk is lane<32 (not <48;
// the 48-lane tail overwrote the other buffer's kc9 K sub-tile -> absmax .24)
__global__ __launch_bounds__(512, 2)
void attn8(char* __restrict__ dout, const char* __restrict__ tiles,
           const float* __restrict__ ocr, const int* __restrict__ mask,
           const float* __restrict__ lnw, const float* __restrict__ lnb)
{
    __shared__ __align__(16) char Tb[2][TSZ];
    const int t = threadIdx.x;
    const int w = t >> 6, lane = t & 63, ln = lane & 15, quad = lane >> 4;
    const int b = blockIdx.x, n0 = blockIdx.y*128;  // same-b blocks share an XCD
    const int nlane = n0 + w*16 + ln;

    // Q B-frags from d_out low bytes (prescaled by 1/sqrt(300))
    const char* qb = dout + (size_t)(b*Nn + nlane)*1200;
    bfrag qf[10];
    #pragma unroll
    for (int kc = 0; kc < 9; ++kc)
        qf[kc] = *(const bfrag*)(qb + kc*64 + quad*16);
    {
        BF z; z.u[0]=z.u[1]=z.u[2]=z.u[3]=0;
        if (quad < 2) z.q = *(const u4*)(qb + 576 + quad*16);
        qf[9] = z.v;
    }

    f4 oacc[19];
    #pragma unroll
    for (int i = 0; i < 19; ++i) oacc[i] = (f4){0.f,0.f,0.f,0.f};
    float lrun = 0.f;
    const char* tb = tiles + (size_t)b*16*TSZ;

    // stage one full 38400-B merged tile: 37 x 1KB chunks + 512-B tail (32 ln)
#define STAGE_TILE(SRC, DST) do { \
        const char* s_ = (SRC); char* d_ = (DST); \
        for (int c = w; c < 38; c += 8) \
            if (c < 37 || lane < 32) \
                async16(s_ + c*1024 + lane*16, d_ + c*1024 + lane*16); \
    } while (0)

    STAGE_TILE(tb, Tb[0]);               // tile 0
    __syncthreads();

    for (int mt = 0; mt < 16; ++mt) {
        const char* Kz = Tb[mt & 1];
        const char* Vz = Kz + VOFF;

        // issue stage of tile mt+1 into the free buffer; drained by the
        // end-of-phase barrier a full QK^T+softmax+PV later
        if (mt < 15) STAGE_TILE(tb + (size_t)(mt+1)*TSZ, Tb[1 - (mt & 1)]);

        // S^T: A = K rows (m), B = Q  ->  C: row=m=quad*4+reg, col=n=ln
        f4 slo = (f4){0.f,0.f,0.f,0.f}, shi = (f4){0.f,0.f,0.f,0.f};
        __builtin_amdgcn_s_setprio(1);
        #pragma unroll
        for (int kc = 0; kc < 9; ++kc) {
            bfrag alo = *(const bfrag*)(Kz + 768 + kc*2048 + quad*512 + ln*16);
            bfrag ahi = *(const bfrag*)(Kz + 768 + kc*2048 + quad*512 + 256 + ln*16);
            slo = __builtin_amdgcn_mfma_f32_16x16x32_bf16(alo, qf[kc], slo, 0,0,0);
            shi = __builtin_amdgcn_mfma_f32_16x16x32_bf16(ahi, qf[kc], shi, 0,0,0);
        }
        {   // kc = 9 from 24B-row sub-tile (k>=300 garbage killed by Q zeros)
            BF alo, ahi;
            alo.u[0]=alo.u[1]=alo.u[2]=alo.u[3]=0;
            ahi.u[0]=ahi.u[1]=ahi.u[2]=ahi.u[3]=0;
            if (quad < 2) {
                u2 x0 = *(const u2*)(Kz + ln*24 + quad*16);
                u2 x1 = *(const u2*)(Kz + ln*24 + quad*16 + 8);
                alo.u[0]=x0.x; alo.u[1]=x0.y; alo.u[2]=x1.x; alo.u[3]=x1.y;
                u2 y0 = *(const u2*)(Kz + (16+ln)*24 + quad*16);
                u2 y1 = *(const u2*)(Kz + (16+ln)*24 + quad*16 + 8);
                ahi.u[0]=y0.x; ahi.u[1]=y0.y; ahi.u[2]=y1.x; ahi.u[3]=y1.y;
            }
            slo = __builtin_amdgcn_mfma_f32_16x16x32_bf16(alo.v, qf[9], slo, 0,0,0);
            shi = __builtin_amdgcn_mfma_f32_16x16x32_bf16(ahi.v, qf[9], shi, 0,0,0);
        }
        __builtin_amdgcn_s_setprio(0);

        // unnormalized softmax: p = exp(s), l += sum(p)  (register-only)
        float elo[4], ehi[4], ls = 0.f;
        #pragma unroll
        for (int reg = 0; reg < 4; ++reg) {
            elo[reg] = __expf(slo[reg]);
            ehi[reg] = __expf(shi[reg]);
            ls += elo[reg] + ehi[reg];
        }
        ls += __shfl_xor(ls, 16);
        ls += __shfl_xor(ls, 32);
        lrun += ls;

        // P: C-layout -> A-layout in-register (8 shfl + select)
        unsigned lo01 = pk_rne(elo[0], elo[1]), lo23 = pk_rne(elo[2], elo[3]);
        unsigned hi01 = pk_rne(ehi[0], ehi[1]), hi23 = pk_rne(ehi[2], ehi[3]);
        int sA = 2*(quad & 1)*16 + ln, sB = sA + 16;
        unsigned l0 = (unsigned)__shfl((int)lo01, sA);
        unsigned l1 = (unsigned)__shfl((int)lo23, sA);
        unsigned l2 = (unsigned)__shfl((int)lo01, sB);
        unsigned l3 = (unsigned)__shfl((int)lo23, sB);
        unsigned h0 = (unsigned)__shfl((int)hi01, sA);
        unsigned h1 = (unsigned)__shfl((int)hi23, sA);
        unsigned h2 = (unsigned)__shfl((int)hi01, sB);
        unsigned h3 = (unsigned)__shfl((int)hi23, sB);
        BF p;
        bool useHi = quad >= 2;
        p.u[0] = useHi ? h0 : l0; p.u[1] = useHi ? h1 : l1;
        p.u[2] = useHi ? h2 : l2; p.u[3] = useHi ? h3 : l3;

        // O += P V : B-frags from V zone of the LDS tile
        __builtin_amdgcn_s_setprio(1);
        #pragma unroll
        for (int nt = 0; nt < 18; ++nt) {
            bfrag vf = *(const bfrag*)(Vz + nt*1024 + lane*16);
            oacc[nt] = __builtin_amdgcn_mfma_f32_16x16x32_bf16(p.v, vf, oacc[nt], 0,0,0);
        }
        {   // nt = 18: d 288..303, ln >= 12 has no storage -> zero frag
            BF vf; vf.u[0]=vf.u[1]=vf.u[2]=vf.u[3]=0;
            if (ln < 12) vf.q = *(const u4*)(Vz + 18432 + quad*192 + ln*16);
            oacc[18] = __builtin_amdgcn_mfma_f32_16x16x32_bf16(p.v, vf.v, oacc[18], 0,0,0);
        }
        __builtin_amdgcn_s_setprio(0);

        __syncthreads();   // drains stage(mt+1); marks current buffer free
    }

    // epilogue: rows n = quad*4+reg; cols d = nt*16+ln
    float invl[4];
    #pragma unroll
    for (int reg = 0; reg < 4; ++reg) invl[reg] = 1.0f / __shfl(lrun, quad*4 + reg);
    #pragma unroll
    for (int reg = 0; reg < 4; ++reg) {
        int r = b*Nn + n0 + w*16 + quad*4 + reg;
        int mr = mask[r];
        float xs[19], s = 0.f, ss = 0.f;
        #pragma unroll
        for (int nt = 0; nt < 19; ++nt) {
            int d = nt*16 + ln;
            float x = 0.f;
            if (d < Dd) x = oacc[nt][reg]*invl[reg] + ocr[(size_t)r*Dd + d];
            xs[nt] = x; s += x; ss += x*x;
        }
        #pragma unroll
        for (int off = 1; off < 16; off <<= 1) {
            s += __shfl_xor(s, off); ss += __shfl_xor(ss, off);
        }
        float mu   = s * (1.0f/Dd);
        float var  = ss * (1.0f/Dd) - mu*mu;
        float rstd = rsqrtf(var + 1e-5f);
        #pragma unroll
        for (int nt = 0; nt < 19; ++nt) {
            int d = nt*16 + ln;
            if (d < Dd) {
                // masked rows: +lnw+lnb (verified rounds 1-3)
                float y = mr ? (xs[nt]-mu)*rstd*lnw[d] + lnb[d] : lnw[d] + lnb[d];
                *(float*)(dout + (size_t)r*1200 + d*4) = y;
            }
        }
    }
}

extern "C" void kernel_launch(void* const* d_in, const int* in_sizes, int n_in,
                              void* d_out, int out_size, void* d_ws, size_t ws_size,
                              hipStream_t stream)
{
    const float* concepts = (const float*)d_in[0];
    const float* ocr      = (const float*)d_in[1];
    const int*   mask     = (const int*)d_in[2];
    const float* wq  = (const float*)d_in[3];
    const float* bq  = (const float*)d_in[4];
    const float* wk  = (const float*)d_in[5];
    const float* bk  = (const float*)d_in[6];
    const float* lnw = (const float*)d_in[7];
    const float* lnb = (const float*)d_in[8];

    char* dout  = (char*)d_out;
    char* tiles = (char*)d_ws;   // 1024 merged tiles x 38400 B = 39,321,600 B

    prep <<<dim3(1064),    256, 0, stream>>>(concepts, tiles, wq, wk, dout);
    proj4<<<dim3(512, 2),  256, 0, stream>>>(concepts, ocr, bq, bk, dout, tiles);
    attn8<<<dim3(64, 4),   512, 0, stream>>>(dout, tiles, ocr, mask, lnw, lnb);
}

// Round 5
// 213.046 us; speedup vs baseline: 1.0887x; 1.0650x over previous
//
#include <hip/hip_runtime.h>
#include <math.h>

#define Bb 64
#define Nn 512
#define Dd 300

typedef __attribute__((ext_vector_type(8))) short bfrag;   // 8 bf16 = 4 VGPRs
typedef __attribute__((ext_vector_type(4))) float f4;      // MFMA accumulator
typedef __attribute__((ext_vector_type(4))) unsigned u4;
typedef __attribute__((ext_vector_type(2))) unsigned u2;

union BF { unsigned u[4]; bfrag v; u4 q; };

__device__ inline unsigned bfr(float x){            // f32 -> bf16 bits, RNE
    union{float f;unsigned u;}v; v.f=x;
    return (v.u + 0x7FFFu + ((v.u>>16)&1u))>>16;
}
__device__ inline unsigned pk_rne(float a, float b){ return bfr(a) | (bfr(b)<<16); }
__device__ inline unsigned pk_tr(float a, float b){  // truncation pack (cheap)
    union{float f;unsigned u;} ua, ub; ua.f=a; ub.f=b;
    return (ua.u>>16) | (ub.u & 0xFFFF0000u);
}
// W-frag bytes live in d_out slot bytes [608, 608+512) of slots f>>9
__device__ inline char* wadr(char* dout, unsigned f){
    return dout + (size_t)(f>>9)*1200u + 608u + (f&511u);
}
__device__ inline void async16(const char* g, char* l){
    __builtin_amdgcn_global_load_lds(
        (const __attribute__((address_space(1))) void*)g,
        (__attribute__((address_space(3))) void*)l, 16, 0, 0);
}

// Merged (b,mt) tile: 38400 B = [K zone 19200 | V zone 19200]
//  K: kc9 sub-tile [0,768): m*24 + (e-288)*2
//     kc<9:  768 + kc*2048 + ((e>>3)&3)*512 + m*16 + (e&7)*2
//  V: d<288:  19200 + (d>>4)*1024 + (m>>3)*256 + (d&15)*16 + (m&7)*2
//     d>=288: 19200 + 18432 + (m>>3)*192 + (d-288)*16 + (m&7)*2
#define TSZ 38400
#define VOFF 19200

// ---------- Kernel A: W -> bf16 frag-tiles in d_out high bytes -------------
// f = sel*194560 + kc*19456 + g*4864 + n*16  (+ (k&7)*2 inside)
__global__ __launch_bounds__(256)
void wprep(const float* __restrict__ wq, const float* __restrict__ wk,
           char* __restrict__ dout)
{
    const int sel = blockIdx.x / 10, kc = blockIdx.x % 10;
    const float* W = sel ? wk : wq;
    const int n = blockIdx.y*152 + threadIdx.x;
    if (threadIdx.x < 152 && n < 304) {
        unsigned uu[16];
        #pragma unroll
        for (int j = 0; j < 16; ++j) uu[j] = 0;
        if (n < Dd) {
            const float* wr = W + (size_t)n*Dd + kc*32;
            int nv4 = (kc < 9) ? 8 : 3;        // kc=9: k 288..299 only
            #pragma unroll
            for (int i = 0; i < 8; ++i) {
                if (i < nv4) {
                    float4 v = *(const float4*)(wr + i*4);
                    uu[2*i  ] = pk_rne(v.x, v.y);
                    uu[2*i+1] = pk_rne(v.z, v.w);
                }
            }
        }
        unsigned fb = (unsigned)(sel*194560 + kc*19456 + n*16);
        #pragma unroll
        for (int g = 0; g < 4; ++g) {
            u4 q; q.x = uu[4*g+0]; q.y = uu[4*g+1]; q.z = uu[4*g+2]; q.w = uu[4*g+3];
            *(u4*)wadr(dout, fb + g*4864) = q;
        }
    }
}

// ---------- Kernel B: fused projection GEMM (blocks 0..511) +  -------------
//            concepts->V-zone cast (blocks 512..1023, 2 tiles each)
// The V-cast is data-independent of the projection; fusing lets it fill CU
// idle time instead of running as a serial launch. Projection: 128 rows per
// 8-wave block (staging + barriers amortized 2x vs 64-row blocks).
// Q is pre-scaled by 1/sqrt(300) so attention needs no scale.
__global__ __launch_bounds__(512)
void projcast(const float* __restrict__ concepts, const float* __restrict__ ocr,
              const float* __restrict__ bq, const float* __restrict__ bk,
              char* __restrict__ dout, char* __restrict__ tiles)
{
    __shared__ char Wl[2][19456];
    const int bx = blockIdx.x;
    const int t  = threadIdx.x;

    if (bx >= 512) {
        // ---- V-cast role: two (b,mt) tiles per block ----
        const int half = t >> 8, tt = t & 255;
        const int tileIdx = (bx - 512)*2 + half;
        const int mt = tileIdx & 15, b = tileIdx >> 4;
        char* vz = tiles + ((size_t)(b*16 + mt))*TSZ + VOFF;
        for (int task = tt; task < 300; task += 256) {
            int m8 = task / 75, d4 = task - m8*75;     // m8:0..3, d4:0..74
            const float* src = concepts + ((size_t)(b*Nn + mt*32 + m8*8))*Dd + d4*4;
            float4 r[8];
            #pragma unroll
            for (int i = 0; i < 8; ++i) r[i] = *(const float4*)(src + (size_t)i*Dd);
            #pragma unroll
            for (int dd = 0; dd < 4; ++dd) {
                int d = d4*4 + dd;
                float x[8];
                #pragma unroll
                for (int i = 0; i < 8; ++i)
                    x[i] = (dd==0) ? r[i].x : (dd==1) ? r[i].y : (dd==2) ? r[i].z : r[i].w;
                u4 q; q.x = pk_rne(x[0],x[1]); q.y = pk_rne(x[2],x[3]);
                      q.z = pk_rne(x[4],x[5]); q.w = pk_rne(x[6],x[7]);
                char* dst = (d < 288)
                    ? vz + (d>>4)*1024 + m8*256 + (d&15)*16
                    : vz + 18432 + m8*192 + (d-288)*16;
                *(u4*)dst = q;
            }
        }
        return;
    }

    // ---- projection role: 128 rows, 8 waves ----
    const int w = t >> 6, lane = t & 63, ln = lane & 15, quad = lane >> 4;
    const int sel = bx >> 8;
    const float* X    = sel ? ocr : concepts;
    const float* bias = sel ? bk  : bq;
    const int r0w = (bx & 255)*128 + w*16;
    const float* xr = X + (size_t)(r0w + ln)*Dd;

    const unsigned selbase = (unsigned)sel*194560u;
    #define STAGE_W8(buf, kc) \
        for (int c = w; c < 19; c += 8) \
            async16((const char*)wadr(dout, selbase + (unsigned)(kc)*19456u + c*1024u + lane*16u), \
                    &Wl[buf][c*1024 + lane*16]);

    f4 acc[19];
    #pragma unroll
    for (int i = 0; i < 19; ++i) acc[i] = (f4){0.f,0.f,0.f,0.f};

    STAGE_W8(0, 0);
    __syncthreads();

    for (int kc = 0; kc < 10; ++kc) {
        const int cur = kc & 1;
        if (kc < 9) { STAGE_W8(1 - cur, kc + 1); }
        BF a;
        if (kc < 9) {
            float4 v0 = *(const float4*)(xr + kc*32 + quad*8);
            float4 v1 = *(const float4*)(xr + kc*32 + quad*8 + 4);
            a.u[0]=pk_tr(v0.x,v0.y); a.u[1]=pk_tr(v0.z,v0.w);
            a.u[2]=pk_tr(v1.x,v1.y); a.u[3]=pk_tr(v1.z,v1.w);
        } else {
            a.u[0]=0; a.u[1]=0; a.u[2]=0; a.u[3]=0;
            if (quad == 0) {
                float4 v0 = *(const float4*)(xr + 288);
                float4 v1 = *(const float4*)(xr + 292);
                a.u[0]=pk_tr(v0.x,v0.y); a.u[1]=pk_tr(v0.z,v0.w);
                a.u[2]=pk_tr(v1.x,v1.y); a.u[3]=pk_tr(v1.z,v1.w);
            } else if (quad == 1) {
                float4 v0 = *(const float4*)(xr + 296);
                a.u[0]=pk_tr(v0.x,v0.y); a.u[1]=pk_tr(v0.z,v0.w);
            }
        }
        #pragma unroll
        for (int nt = 0; nt < 19; ++nt) {
            BF bfv; bfv.q = *(const u4*)&Wl[cur][quad*4864 + nt*256 + ln*16];
            acc[nt] = __builtin_amdgcn_mfma_f32_16x16x32_bf16(a.v, bfv.v, acc[nt], 0,0,0);
        }
        __syncthreads();
    }

    const float QSCALE = 0.057735026918962584f;   // 1/sqrt(300)
    #pragma unroll
    for (int nt = 0; nt < 19; ++nt) {
        int e = nt*16 + ln;
        if (sel == 0) {
            #pragma unroll
            for (int reg = 0; reg < 4; ++reg) {
                int r = r0w + quad*4 + reg;
                short val = (e < Dd) ? (short)bfr((acc[nt][reg] + bias[e])*QSCALE) : (short)0;
                *(short*)(dout + (size_t)r*1200 + e*2) = val;   // e 300..303 zeroed
            }
        } else if (e < Dd) {
            float bv = bias[e];
            #pragma unroll
            for (int reg = 0; reg < 4; ++reg) {
                int r = r0w + quad*4 + reg;
                int b = r >> 9, m = r & 511, mt = m >> 5, ml = m & 31;
                char* tile = tiles + ((size_t)(b*16 + mt))*TSZ;
                short val = (short)bfr(acc[nt][reg] + bv);
                if (e < 288)
                    *(short*)(tile + 768 + (e>>5)*2048 + ((e>>3)&3)*512 + ml*16 + (e&7)*2) = val;
                else
                    *(short*)(tile + ml*24 + (e-288)*2) = val;
            }
        }
    }
}

// ---------- Kernel D: 8-wave flash attention, tile staged once per block ---
// (unchanged from round 4 -- passing at 64 us)
//  - 512-thread / 8-wave blocks, 128 Q rows each -> grid (64,4) = 1 block/CU
//  - full 38.4 KB merged tile staged ONCE per phase for all 8 waves
//  - single-barrier double-buffer schedule (LDS 76.8 KB)
//  - tail chunk: 38400 = 37*1024 + 512 -> lane<32
__global__ __launch_bounds__(512, 2)
void attn8(char* __restrict__ dout, const char* __restrict__ tiles,
           const float* __restrict__ ocr, const int* __restrict__ mask,
           const float* __restrict__ lnw, const float* __restrict__ lnb)
{
    __shared__ __align__(16) char Tb[2][TSZ];
    const int t = threadIdx.x;
    const int w = t >> 6, lane = t & 63, ln = lane & 15, quad = lane >> 4;
    const int b = blockIdx.x, n0 = blockIdx.y*128;  // same-b blocks share an XCD
    const int nlane = n0 + w*16 + ln;

    // Q B-frags from d_out low bytes (prescaled by 1/sqrt(300))
    const char* qb = dout + (size_t)(b*Nn + nlane)*1200;
    bfrag qf[10];
    #pragma unroll
    for (int kc = 0; kc < 9; ++kc)
        qf[kc] = *(const bfrag*)(qb + kc*64 + quad*16);
    {
        BF z; z.u[0]=z.u[1]=z.u[2]=z.u[3]=0;
        if (quad < 2) z.q = *(const u4*)(qb + 576 + quad*16);
        qf[9] = z.v;
    }

    f4 oacc[19];
    #pragma unroll
    for (int i = 0; i < 19; ++i) oacc[i] = (f4){0.f,0.f,0.f,0.f};
    float lrun = 0.f;
    const char* tb = tiles + (size_t)b*16*TSZ;

    // stage one full 38400-B merged tile: 37 x 1KB chunks + 512-B tail (32 ln)
#define STAGE_TILE(SRC, DST) do { \
        const char* s_ = (SRC); char* d_ = (DST); \
        for (int c = w; c < 38; c += 8) \
            if (c < 37 || lane < 32) \
                async16(s_ + c*1024 + lane*16, d_ + c*1024 + lane*16); \
    } while (0)

    STAGE_TILE(tb, Tb[0]);               // tile 0
    __syncthreads();

    for (int mt = 0; mt < 16; ++mt) {
        const char* Kz = Tb[mt & 1];
        const char* Vz = Kz + VOFF;

        // issue stage of tile mt+1 into the free buffer; drained by the
        // end-of-phase barrier a full QK^T+softmax+PV later
        if (mt < 15) STAGE_TILE(tb + (size_t)(mt+1)*TSZ, Tb[1 - (mt & 1)]);

        // S^T: A = K rows (m), B = Q  ->  C: row=m=quad*4+reg, col=n=ln
        f4 slo = (f4){0.f,0.f,0.f,0.f}, shi = (f4){0.f,0.f,0.f,0.f};
        __builtin_amdgcn_s_setprio(1);
        #pragma unroll
        for (int kc = 0; kc < 9; ++kc) {
            bfrag alo = *(const bfrag*)(Kz + 768 + kc*2048 + quad*512 + ln*16);
            bfrag ahi = *(const bfrag*)(Kz + 768 + kc*2048 + quad*512 + 256 + ln*16);
            slo = __builtin_amdgcn_mfma_f32_16x16x32_bf16(alo, qf[kc], slo, 0,0,0);
            shi = __builtin_amdgcn_mfma_f32_16x16x32_bf16(ahi, qf[kc], shi, 0,0,0);
        }
        {   // kc = 9 from 24B-row sub-tile (k>=300 garbage killed by Q zeros)
            BF alo, ahi;
            alo.u[0]=alo.u[1]=alo.u[2]=alo.u[3]=0;
            ahi.u[0]=ahi.u[1]=ahi.u[2]=ahi.u[3]=0;
            if (quad < 2) {
                u2 x0 = *(const u2*)(Kz + ln*24 + quad*16);
                u2 x1 = *(const u2*)(Kz + ln*24 + quad*16 + 8);
                alo.u[0]=x0.x; alo.u[1]=x0.y; alo.u[2]=x1.x; alo.u[3]=x1.y;
                u2 y0 = *(const u2*)(Kz + (16+ln)*24 + quad*16);
                u2 y1 = *(const u2*)(Kz + (16+ln)*24 + quad*16 + 8);
                ahi.u[0]=y0.x; ahi.u[1]=y0.y; ahi.u[2]=y1.x; ahi.u[3]=y1.y;
            }
            slo = __builtin_amdgcn_mfma_f32_16x16x32_bf16(alo.v, qf[9], slo, 0,0,0);
            shi = __builtin_amdgcn_mfma_f32_16x16x32_bf16(ahi.v, qf[9], shi, 0,0,0);
        }
        __builtin_amdgcn_s_setprio(0);

        // unnormalized softmax: p = exp(s), l += sum(p)  (register-only)
        float elo[4], ehi[4], ls = 0.f;
        #pragma unroll
        for (int reg = 0; reg < 4; ++reg) {
            elo[reg] = __expf(slo[reg]);
            ehi[reg] = __expf(shi[reg]);
            ls += elo[reg] + ehi[reg];
        }
        ls += __shfl_xor(ls, 16);
        ls += __shfl_xor(ls, 32);
        lrun += ls;

        // P: C-layout -> A-layout in-register (8 shfl + select)
        unsigned lo01 = pk_rne(elo[0], elo[1]), lo23 = pk_rne(elo[2], elo[3]);
        unsigned hi01 = pk_rne(ehi[0], ehi[1]), hi23 = pk_rne(ehi[2], ehi[3]);
        int sA = 2*(quad & 1)*16 + ln, sB = sA + 16;
        unsigned l0 = (unsigned)__shfl((int)lo01, sA);
        unsigned l1 = (unsigned)__shfl((int)lo23, sA);
        unsigned l2 = (unsigned)__shfl((int)lo01, sB);
        unsigned l3 = (unsigned)__shfl((int)lo23, sB);
        unsigned h0 = (unsigned)__shfl((int)hi01, sA);
        unsigned h1 = (unsigned)__shfl((int)hi23, sA);
        unsigned h2 = (unsigned)__shfl((int)hi01, sB);
        unsigned h3 = (unsigned)__shfl((int)hi23, sB);
        BF p;
        bool useHi = quad >= 2;
        p.u[0] = useHi ? h0 : l0; p.u[1] = useHi ? h1 : l1;
        p.u[2] = useHi ? h2 : l2; p.u[3] = useHi ? h3 : l3;

        // O += P V : B-frags from V zone of the LDS tile
        __builtin_amdgcn_s_setprio(1);
        #pragma unroll
        for (int nt = 0; nt < 18; ++nt) {
            bfrag vf = *(const bfrag*)(Vz + nt*1024 + lane*16);
            oacc[nt] = __builtin_amdgcn_mfma_f32_16x16x32_bf16(p.v, vf, oacc[nt], 0,0,0);
        }
        {   // nt = 18: d 288..303, ln >= 12 has no storage -> zero frag
            BF vf; vf.u[0]=vf.u[1]=vf.u[2]=vf.u[3]=0;
            if (ln < 12) vf.q = *(const u4*)(Vz + 18432 + quad*192 + ln*16);
            oacc[18] = __builtin_amdgcn_mfma_f32_16x16x32_bf16(p.v, vf.v, oacc[18], 0,0,0);
        }
        __builtin_amdgcn_s_setprio(0);

        __syncthreads();   // drains stage(mt+1); marks current buffer free
    }

    // epilogue: rows n = quad*4+reg; cols d = nt*16+ln
    float invl[4];
    #pragma unroll
    for (int reg = 0; reg < 4; ++reg) invl[reg] = 1.0f / __shfl(lrun, quad*4 + reg);
    #pragma unroll
    for (int reg = 0; reg < 4; ++reg) {
        int r = b*Nn + n0 + w*16 + quad*4 + reg;
        int mr = mask[r];
        float xs[19], s = 0.f, ss = 0.f;
        #pragma unroll
        for (int nt = 0; nt < 19; ++nt) {
            int d = nt*16 + ln;
            float x = 0.f;
            if (d < Dd) x = oacc[nt][reg]*invl[reg] + ocr[(size_t)r*Dd + d];
            xs[nt] = x; s += x; ss += x*x;
        }
        #pragma unroll
        for (int off = 1; off < 16; off <<= 1) {
            s += __shfl_xor(s, off); ss += __shfl_xor(ss, off);
        }
        float mu   = s * (1.0f/Dd);
        float var  = ss * (1.0f/Dd) - mu*mu;
        float rstd = rsqrtf(var + 1e-5f);
        #pragma unroll
        for (int nt = 0; nt < 19; ++nt) {
            int d = nt*16 + ln;
            if (d < Dd) {
                // masked rows: +lnw+lnb (verified rounds 1-3)
                float y = mr ? (xs[nt]-mu)*rstd*lnw[d] + lnb[d] : lnw[d] + lnb[d];
                *(float*)(dout + (size_t)r*1200 + d*4) = y;
            }
        }
    }
}

extern "C" void kernel_launch(void* const* d_in, const int* in_sizes, int n_in,
                              void* d_out, int out_size, void* d_ws, size_t ws_size,
                              hipStream_t stream)
{
    const float* concepts = (const float*)d_in[0];
    const float* ocr      = (const float*)d_in[1];
    const int*   mask     = (const int*)d_in[2];
    const float* wq  = (const float*)d_in[3];
    const float* bq  = (const float*)d_in[4];
    const float* wk  = (const float*)d_in[5];
    const float* bk  = (const float*)d_in[6];
    const float* lnw = (const float*)d_in[7];
    const float* lnb = (const float*)d_in[8];

    char* dout  = (char*)d_out;
    char* tiles = (char*)d_ws;   // 1024 merged tiles x 38400 B = 39,321,600 B

    wprep   <<<dim3(20, 2), 256, 0, stream>>>(wq, wk, dout);
    projcast<<<dim3(1024),  512, 0, stream>>>(concepts, ocr, bq, bk, dout, tiles);
    attn8   <<<dim3(64, 4), 512, 0, stream>>>(dout, tiles, ocr, mask, lnw, lnb);
}

// Round 6
// 210.051 us; speedup vs baseline: 1.1042x; 1.0143x over previous
//
#include <hip/hip_runtime.h>
#include <math.h>

#define Bb 64
#define Nn 512
#define Dd 300

typedef __attribute__((ext_vector_type(8))) short bfrag;   // 8 bf16 = 4 VGPRs
typedef __attribute__((ext_vector_type(4))) float f4;      // MFMA accumulator
typedef __attribute__((ext_vector_type(4))) unsigned u4;
typedef __attribute__((ext_vector_type(2))) unsigned u2;

union BF { unsigned u[4]; bfrag v; u4 q; };

__device__ inline unsigned bfr(float x){            // f32 -> bf16 bits, RNE
    union{float f;unsigned u;}v; v.f=x;
    return (v.u + 0x7FFFu + ((v.u>>16)&1u))>>16;
}
__device__ inline unsigned pk_rne(float a, float b){ return bfr(a) | (bfr(b)<<16); }
__device__ inline unsigned pk_tr(float a, float b){  // truncation pack (cheap)
    union{float f;unsigned u;} ua, ub; ua.f=a; ub.f=b;
    return (ua.u>>16) | (ub.u & 0xFFFF0000u);
}
// W-frag bytes live in d_out slot bytes [608, 608+512) of slots f>>9
__device__ inline char* wadr(char* dout, unsigned f){
    return dout + (size_t)(f>>9)*1200u + 608u + (f&511u);
}
__device__ inline void async16(const char* g, char* l){
    __builtin_amdgcn_global_load_lds(
        (const __attribute__((address_space(1))) void*)g,
        (__attribute__((address_space(3))) void*)l, 16, 0, 0);
}

// Merged (b,mt) tile: 38400 B = [K zone 19200 | V zone 19200]
//  K: kc9 sub-tile [0,768): m*24 + (e-288)*2
//     kc<9:  768 + kc*2048 + ((e>>3)&3)*512 + m*16 + (e&7)*2
//  V: d<288:  19200 + (d>>4)*1024 + (m>>3)*256 + (d&15)*16 + (m&7)*2
//     d>=288: 19200 + 18432 + (m>>3)*192 + (d-288)*16 + (m&7)*2
#define TSZ 38400
#define VOFF 19200

// ---------- Kernel A: W -> bf16 frag-tiles in d_out high bytes -------------
// f = sel*194560 + kc*19456 + g*4864 + n*16  (+ (k&7)*2 inside)
__global__ __launch_bounds__(256)
void wprep(const float* __restrict__ wq, const float* __restrict__ wk,
           char* __restrict__ dout)
{
    const int sel = blockIdx.x / 10, kc = blockIdx.x % 10;
    const float* W = sel ? wk : wq;
    const int n = blockIdx.y*152 + threadIdx.x;
    if (threadIdx.x < 152 && n < 304) {
        unsigned uu[16];
        #pragma unroll
        for (int j = 0; j < 16; ++j) uu[j] = 0;
        if (n < Dd) {
            const float* wr = W + (size_t)n*Dd + kc*32;
            int nv4 = (kc < 9) ? 8 : 3;        // kc=9: k 288..299 only
            #pragma unroll
            for (int i = 0; i < 8; ++i) {
                if (i < nv4) {
                    float4 v = *(const float4*)(wr + i*4);
                    uu[2*i  ] = pk_rne(v.x, v.y);
                    uu[2*i+1] = pk_rne(v.z, v.w);
                }
            }
        }
        unsigned fb = (unsigned)(sel*194560 + kc*19456 + n*16);
        #pragma unroll
        for (int g = 0; g < 4; ++g) {
            u4 q; q.x = uu[4*g+0]; q.y = uu[4*g+1]; q.z = uu[4*g+2]; q.w = uu[4*g+3];
            *(u4*)wadr(dout, fb + g*4864) = q;
        }
    }
}

// ---------- Kernel B: fused projection GEMM (blocks 0..511) +  -------------
//            concepts->V-zone cast (blocks 512..1023, 2 tiles each)
__global__ __launch_bounds__(512)
void projcast(const float* __restrict__ concepts, const float* __restrict__ ocr,
              const float* __restrict__ bq, const float* __restrict__ bk,
              char* __restrict__ dout, char* __restrict__ tiles)
{
    __shared__ char Wl[2][19456];
    const int bx = blockIdx.x;
    const int t  = threadIdx.x;

    if (bx >= 512) {
        // ---- V-cast role: two (b,mt) tiles per block ----
        const int half = t >> 8, tt = t & 255;
        const int tileIdx = (bx - 512)*2 + half;
        const int mt = tileIdx & 15, b = tileIdx >> 4;
        char* vz = tiles + ((size_t)(b*16 + mt))*TSZ + VOFF;
        for (int task = tt; task < 300; task += 256) {
            int m8 = task / 75, d4 = task - m8*75;     // m8:0..3, d4:0..74
            const float* src = concepts + ((size_t)(b*Nn + mt*32 + m8*8))*Dd + d4*4;
            float4 r[8];
            #pragma unroll
            for (int i = 0; i < 8; ++i) r[i] = *(const float4*)(src + (size_t)i*Dd);
            #pragma unroll
            for (int dd = 0; dd < 4; ++dd) {
                int d = d4*4 + dd;
                float x[8];
                #pragma unroll
                for (int i = 0; i < 8; ++i)
                    x[i] = (dd==0) ? r[i].x : (dd==1) ? r[i].y : (dd==2) ? r[i].z : r[i].w;
                u4 q; q.x = pk_rne(x[0],x[1]); q.y = pk_rne(x[2],x[3]);
                      q.z = pk_rne(x[4],x[5]); q.w = pk_rne(x[6],x[7]);
                char* dst = (d < 288)
                    ? vz + (d>>4)*1024 + m8*256 + (d&15)*16
                    : vz + 18432 + m8*192 + (d-288)*16;
                *(u4*)dst = q;
            }
        }
        return;
    }

    // ---- projection role: 128 rows, 8 waves ----
    const int w = t >> 6, lane = t & 63, ln = lane & 15, quad = lane >> 4;
    const int sel = bx >> 8;
    const float* X    = sel ? ocr : concepts;
    const float* bias = sel ? bk  : bq;
    const int r0w = (bx & 255)*128 + w*16;
    const float* xr = X + (size_t)(r0w + ln)*Dd;

    const unsigned selbase = (unsigned)sel*194560u;
    #define STAGE_W8(buf, kc) \
        for (int c = w; c < 19; c += 8) \
            async16((const char*)wadr(dout, selbase + (unsigned)(kc)*19456u + c*1024u + lane*16u), \
                    &Wl[buf][c*1024 + lane*16]);

    f4 acc[19];
    #pragma unroll
    for (int i = 0; i < 19; ++i) acc[i] = (f4){0.f,0.f,0.f,0.f};

    STAGE_W8(0, 0);
    __syncthreads();

    for (int kc = 0; kc < 10; ++kc) {
        const int cur = kc & 1;
        if (kc < 9) { STAGE_W8(1 - cur, kc + 1); }
        BF a;
        if (kc < 9) {
            float4 v0 = *(const float4*)(xr + kc*32 + quad*8);
            float4 v1 = *(const float4*)(xr + kc*32 + quad*8 + 4);
            a.u[0]=pk_tr(v0.x,v0.y); a.u[1]=pk_tr(v0.z,v0.w);
            a.u[2]=pk_tr(v1.x,v1.y); a.u[3]=pk_tr(v1.z,v1.w);
        } else {
            a.u[0]=0; a.u[1]=0; a.u[2]=0; a.u[3]=0;
            if (quad == 0) {
                float4 v0 = *(const float4*)(xr + 288);
                float4 v1 = *(const float4*)(xr + 292);
                a.u[0]=pk_tr(v0.x,v0.y); a.u[1]=pk_tr(v0.z,v0.w);
                a.u[2]=pk_tr(v1.x,v1.y); a.u[3]=pk_tr(v1.z,v1.w);
            } else if (quad == 1) {
                float4 v0 = *(const float4*)(xr + 296);
                a.u[0]=pk_tr(v0.x,v0.y); a.u[1]=pk_tr(v0.z,v0.w);
            }
        }
        #pragma unroll
        for (int nt = 0; nt < 19; ++nt) {
            BF bfv; bfv.q = *(const u4*)&Wl[cur][quad*4864 + nt*256 + ln*16];
            acc[nt] = __builtin_amdgcn_mfma_f32_16x16x32_bf16(a.v, bfv.v, acc[nt], 0,0,0);
        }
        __syncthreads();
    }

    const float QSCALE = 0.057735026918962584f;   // 1/sqrt(300)
    #pragma unroll
    for (int nt = 0; nt < 19; ++nt) {
        int e = nt*16 + ln;
        if (sel == 0) {
            #pragma unroll
            for (int reg = 0; reg < 4; ++reg) {
                int r = r0w + quad*4 + reg;
                short val = (e < Dd) ? (short)bfr((acc[nt][reg] + bias[e])*QSCALE) : (short)0;
                *(short*)(dout + (size_t)r*1200 + e*2) = val;   // e 300..303 zeroed
            }
        } else if (e < Dd) {
            float bv = bias[e];
            #pragma unroll
            for (int reg = 0; reg < 4; ++reg) {
                int r = r0w + quad*4 + reg;
                int b = r >> 9, m = r & 511, mt = m >> 5, ml = m & 31;
                char* tile = tiles + ((size_t)(b*16 + mt))*TSZ;
                short val = (short)bfr(acc[nt][reg] + bv);
                if (e < 288)
                    *(short*)(tile + 768 + (e>>5)*2048 + ((e>>3)&3)*512 + ml*16 + (e&7)*2) = val;
                else
                    *(short*)(tile + ml*24 + (e-288)*2) = val;
            }
        }
    }
}

// ---------- Kernel D: 8-wave flash attention, tile-PAIR phases -------------
// Round-5 experiment: halve phase count at constant bytes to split the
// confound {per-phase overhead} vs {fabric throughput}. Stage two contiguous
// merged tiles (76800 B = 75 x 1KB, no tail) per phase into a 2 x 76.8 KB
// LDS double buffer (153.6 KB <= 160 KB, 1 block/CU as before). 8 phases,
// 2 inner sub-tile compute passes (byte-identical to attn8's), 1 barrier
// per pair. If attn stays ~64 us -> throughput-bound on tile bytes.
__global__ __launch_bounds__(512, 2)
void attn9(char* __restrict__ dout, const char* __restrict__ tiles,
           const float* __restrict__ ocr, const int* __restrict__ mask,
           const float* __restrict__ lnw, const float* __restrict__ lnb)
{
    __shared__ __align__(16) char Tb[2][2*TSZ];
    const int t = threadIdx.x;
    const int w = t >> 6, lane = t & 63, ln = lane & 15, quad = lane >> 4;
    const int b = blockIdx.x, n0 = blockIdx.y*128;  // same-b blocks share an XCD
    const int nlane = n0 + w*16 + ln;

    // Q B-frags from d_out low bytes (prescaled by 1/sqrt(300))
    const char* qb = dout + (size_t)(b*Nn + nlane)*1200;
    bfrag qf[10];
    #pragma unroll
    for (int kc = 0; kc < 9; ++kc)
        qf[kc] = *(const bfrag*)(qb + kc*64 + quad*16);
    {
        BF z; z.u[0]=z.u[1]=z.u[2]=z.u[3]=0;
        if (quad < 2) z.q = *(const u4*)(qb + 576 + quad*16);
        qf[9] = z.v;
    }

    f4 oacc[19];
    #pragma unroll
    for (int i = 0; i < 19; ++i) oacc[i] = (f4){0.f,0.f,0.f,0.f};
    float lrun = 0.f;
    const char* tb = tiles + (size_t)b*16*TSZ;

    // stage a tile PAIR: 76800 B = 75 full 1KB chunks (no tail predicate)
#define STAGE_PAIR(SRC, DST) do { \
        const char* s_ = (SRC); char* d_ = (DST); \
        for (int c = w; c < 75; c += 8) \
            async16(s_ + c*1024 + lane*16, d_ + c*1024 + lane*16); \
    } while (0)

    STAGE_PAIR(tb, Tb[0]);               // tiles 0,1
    __syncthreads();

    for (int pr = 0; pr < 8; ++pr) {
        // issue stage of pair pr+1 into the free buffer; drained by the
        // end-of-phase barrier two full QK^T+softmax+PV passes later
        if (pr < 7) STAGE_PAIR(tb + (size_t)(pr + 1)*2*TSZ, Tb[1 - (pr & 1)]);

        #pragma unroll
        for (int sub = 0; sub < 2; ++sub) {
            const char* Kz = Tb[pr & 1] + sub*TSZ;
            const char* Vz = Kz + VOFF;

            // S^T: A = K rows (m), B = Q  ->  C: row=m=quad*4+reg, col=n=ln
            f4 slo = (f4){0.f,0.f,0.f,0.f}, shi = (f4){0.f,0.f,0.f,0.f};
            __builtin_amdgcn_s_setprio(1);
            #pragma unroll
            for (int kc = 0; kc < 9; ++kc) {
                bfrag alo = *(const bfrag*)(Kz + 768 + kc*2048 + quad*512 + ln*16);
                bfrag ahi = *(const bfrag*)(Kz + 768 + kc*2048 + quad*512 + 256 + ln*16);
                slo = __builtin_amdgcn_mfma_f32_16x16x32_bf16(alo, qf[kc], slo, 0,0,0);
                shi = __builtin_amdgcn_mfma_f32_16x16x32_bf16(ahi, qf[kc], shi, 0,0,0);
            }
            {   // kc = 9 from 24B-row sub-tile (k>=300 garbage killed by Q zeros)
                BF alo, ahi;
                alo.u[0]=alo.u[1]=alo.u[2]=alo.u[3]=0;
                ahi.u[0]=ahi.u[1]=ahi.u[2]=ahi.u[3]=0;
                if (quad < 2) {
                    u2 x0 = *(const u2*)(Kz + ln*24 + quad*16);
                    u2 x1 = *(const u2*)(Kz + ln*24 + quad*16 + 8);
                    alo.u[0]=x0.x; alo.u[1]=x0.y; alo.u[2]=x1.x; alo.u[3]=x1.y;
                    u2 y0 = *(const u2*)(Kz + (16+ln)*24 + quad*16);
                    u2 y1 = *(const u2*)(Kz + (16+ln)*24 + quad*16 + 8);
                    ahi.u[0]=y0.x; ahi.u[1]=y0.y; ahi.u[2]=y1.x; ahi.u[3]=y1.y;
                }
                slo = __builtin_amdgcn_mfma_f32_16x16x32_bf16(alo.v, qf[9], slo, 0,0,0);
                shi = __builtin_amdgcn_mfma_f32_16x16x32_bf16(ahi.v, qf[9], shi, 0,0,0);
            }
            __builtin_amdgcn_s_setprio(0);

            // unnormalized softmax: p = exp(s), l += sum(p)  (register-only)
            float elo[4], ehi[4], ls = 0.f;
            #pragma unroll
            for (int reg = 0; reg < 4; ++reg) {
                elo[reg] = __expf(slo[reg]);
                ehi[reg] = __expf(shi[reg]);
                ls += elo[reg] + ehi[reg];
            }
            ls += __shfl_xor(ls, 16);
            ls += __shfl_xor(ls, 32);
            lrun += ls;

            // P: C-layout -> A-layout in-register (8 shfl + select)
            unsigned lo01 = pk_rne(elo[0], elo[1]), lo23 = pk_rne(elo[2], elo[3]);
            unsigned hi01 = pk_rne(ehi[0], ehi[1]), hi23 = pk_rne(ehi[2], ehi[3]);
            int sA = 2*(quad & 1)*16 + ln, sB = sA + 16;
            unsigned l0 = (unsigned)__shfl((int)lo01, sA);
            unsigned l1 = (unsigned)__shfl((int)lo23, sA);
            unsigned l2 = (unsigned)__shfl((int)lo01, sB);
            unsigned l3 = (unsigned)__shfl((int)lo23, sB);
            unsigned h0 = (unsigned)__shfl((int)hi01, sA);
            unsigned h1 = (unsigned)__shfl((int)hi23, sA);
            unsigned h2 = (unsigned)__shfl((int)hi01, sB);
            unsigned h3 = (unsigned)__shfl((int)hi23, sB);
            BF p;
            bool useHi = quad >= 2;
            p.u[0] = useHi ? h0 : l0; p.u[1] = useHi ? h1 : l1;
            p.u[2] = useHi ? h2 : l2; p.u[3] = useHi ? h3 : l3;

            // O += P V : B-frags from V zone of the LDS tile
            __builtin_amdgcn_s_setprio(1);
            #pragma unroll
            for (int nt = 0; nt < 18; ++nt) {
                bfrag vf = *(const bfrag*)(Vz + nt*1024 + lane*16);
                oacc[nt] = __builtin_amdgcn_mfma_f32_16x16x32_bf16(p.v, vf, oacc[nt], 0,0,0);
            }
            {   // nt = 18: d 288..303, ln >= 12 has no storage -> zero frag
                BF vf; vf.u[0]=vf.u[1]=vf.u[2]=vf.u[3]=0;
                if (ln < 12) vf.q = *(const u4*)(Vz + 18432 + quad*192 + ln*16);
                oacc[18] = __builtin_amdgcn_mfma_f32_16x16x32_bf16(p.v, vf.v, oacc[18], 0,0,0);
            }
            __builtin_amdgcn_s_setprio(0);
        }

        __syncthreads();   // drains stage(pr+1); marks current buffer free
    }

    // epilogue: rows n = quad*4+reg; cols d = nt*16+ln
    float invl[4];
    #pragma unroll
    for (int reg = 0; reg < 4; ++reg) invl[reg] = 1.0f / __shfl(lrun, quad*4 + reg);
    #pragma unroll
    for (int reg = 0; reg < 4; ++reg) {
        int r = b*Nn + n0 + w*16 + quad*4 + reg;
        int mr = mask[r];
        float xs[19], s = 0.f, ss = 0.f;
        #pragma unroll
        for (int nt = 0; nt < 19; ++nt) {
            int d = nt*16 + ln;
            float x = 0.f;
            if (d < Dd) x = oacc[nt][reg]*invl[reg] + ocr[(size_t)r*Dd + d];
            xs[nt] = x; s += x; ss += x*x;
        }
        #pragma unroll
        for (int off = 1; off < 16; off <<= 1) {
            s += __shfl_xor(s, off); ss += __shfl_xor(ss, off);
        }
        float mu   = s * (1.0f/Dd);
        float var  = ss * (1.0f/Dd) - mu*mu;
        float rstd = rsqrtf(var + 1e-5f);
        #pragma unroll
        for (int nt = 0; nt < 19; ++nt) {
            int d = nt*16 + ln;
            if (d < Dd) {
                // masked rows: +lnw+lnb (verified rounds 1-3)
                float y = mr ? (xs[nt]-mu)*rstd*lnw[d] + lnb[d] : lnw[d] + lnb[d];
                *(float*)(dout + (size_t)r*1200 + d*4) = y;
            }
        }
    }
}

extern "C" void kernel_launch(void* const* d_in, const int* in_sizes, int n_in,
                              void* d_out, int out_size, void* d_ws, size_t ws_size,
                              hipStream_t stream)
{
    const float* concepts = (const float*)d_in[0];
    const float* ocr      = (const float*)d_in[1];
    const int*   mask     = (const int*)d_in[2];
    const float* wq  = (const float*)d_in[3];
    const float* bq  = (const float*)d_in[4];
    const float* wk  = (const float*)d_in[5];
    const float* bk  = (const float*)d_in[6];
    const float* lnw = (const float*)d_in[7];
    const float* lnb = (const float*)d_in[8];

    char* dout  = (char*)d_out;
    char* tiles = (char*)d_ws;   // 1024 merged tiles x 38400 B = 39,321,600 B

    wprep   <<<dim3(20, 2), 256, 0, stream>>>(wq, wk, dout);
    projcast<<<dim3(1024),  512, 0, stream>>>(concepts, ocr, bq, bk, dout, tiles);
    attn9   <<<dim3(64, 4), 512, 0, stream>>>(dout, tiles, ocr, mask, lnw, lnb);
}